// Round 1
// baseline (999.915 us; speedup 1.0000x reference)
//
#include <hip/hip_runtime.h>

#define NN 50000
#define NE 625000
#define IND 512
#define HID 128
#define OUTD 40
#define NL 3

// ---------------- CSR build ----------------

__global__ __launch_bounds__(256) void count_kernel(const int* __restrict__ dst,
                                                    int* __restrict__ deg) {
    int e = blockIdx.x * 256 + threadIdx.x;
    if (e < NE) atomicAdd(&deg[dst[e]], 1);
}

__global__ __launch_bounds__(1024) void scan_kernel(const int* __restrict__ deg,
                                                    int* __restrict__ rp,
                                                    int* __restrict__ cursor) {
    __shared__ int sums[1024];
    const int CH = (NN + 1023) / 1024;  // 49
    int t = threadIdx.x;
    int beg = t * CH;
    int end = beg + CH < NN ? beg + CH : NN;
    int s = 0;
    for (int i = beg; i < end; i++) s += deg[i];
    sums[t] = s;
    __syncthreads();
    for (int off = 1; off < 1024; off <<= 1) {
        int v = (t >= off) ? sums[t - off] : 0;
        __syncthreads();
        sums[t] += v;
        __syncthreads();
    }
    int run = sums[t] - s;  // exclusive prefix
    for (int i = beg; i < end; i++) {
        rp[i] = run;
        cursor[i] = run;
        run += deg[i];
    }
    if (t == 1023) rp[NN] = run;
}

__global__ __launch_bounds__(256) void fill_kernel(const int* __restrict__ src,
                                                   const int* __restrict__ dst,
                                                   const float* __restrict__ ew,
                                                   int* __restrict__ cursor,
                                                   int* __restrict__ csr_src,
                                                   float* __restrict__ csr_w) {
    int e = blockIdx.x * 256 + threadIdx.x;
    if (e < NE) {
        int d = dst[e];
        int pos = atomicAdd(&cursor[d], 1);
        csr_src[pos] = src[e];
        csr_w[pos] = ew[e];
    }
}

// ---------------- Embedding GEMM: [NN,512] @ [512,128] + b ----------------
// 256 thr, BM=64 rows x BN=128 cols, thread micro-tile 8x4, K chunks of 32.

__global__ __launch_bounds__(256) void emb_gemm(const float* __restrict__ X,
                                                const float* __restrict__ W,
                                                const float* __restrict__ B,
                                                float* __restrict__ H) {
    __shared__ float Xs[32][68];   // k-major, stride 68 (16B aligned, bank-shifted)
    __shared__ float Ws[32][128];
    const int tid = threadIdx.x;
    const int brow = blockIdx.x * 64;
    const int tr = tid >> 5, tc = tid & 31;
    const int row0 = tr * 8, col0 = tc * 4;
    float acc[8][4];
#pragma unroll
    for (int i = 0; i < 8; i++)
#pragma unroll
        for (int j = 0; j < 4; j++) acc[i][j] = 0.f;

    for (int k0 = 0; k0 < IND; k0 += 32) {
#pragma unroll
        for (int j = 0; j < 2; j++) {
            int f = tid + j * 256;      // 0..511 float4s of X tile
            int m = f >> 3;             // row 0..63
            int kk = (f & 7) << 2;      // 0..28
            int g = brow + m;
            float4 v = make_float4(0.f, 0.f, 0.f, 0.f);
            if (g < NN) v = *reinterpret_cast<const float4*>(X + (size_t)g * IND + k0 + kk);
            Xs[kk + 0][m] = v.x; Xs[kk + 1][m] = v.y;
            Xs[kk + 2][m] = v.z; Xs[kk + 3][m] = v.w;
        }
#pragma unroll
        for (int j = 0; j < 4; j++) {
            int f = tid + j * 256;      // 0..1023 float4s of W chunk
            int kk = f >> 5;
            int c4 = (f & 31) << 2;
            *reinterpret_cast<float4*>(&Ws[kk][c4]) =
                *reinterpret_cast<const float4*>(W + (size_t)(k0 + kk) * HID + c4);
        }
        __syncthreads();
#pragma unroll
        for (int kk = 0; kk < 32; kk++) {
            const float4 a0 = *reinterpret_cast<const float4*>(&Xs[kk][row0]);
            const float4 a1 = *reinterpret_cast<const float4*>(&Xs[kk][row0 + 4]);
            const float4 bb = *reinterpret_cast<const float4*>(&Ws[kk][col0]);
            float av[8] = {a0.x, a0.y, a0.z, a0.w, a1.x, a1.y, a1.z, a1.w};
            float bv[4] = {bb.x, bb.y, bb.z, bb.w};
#pragma unroll
            for (int i = 0; i < 8; i++)
#pragma unroll
                for (int j = 0; j < 4; j++) acc[i][j] = fmaf(av[i], bv[j], acc[i][j]);
        }
        __syncthreads();
    }
    const float4 bb = *reinterpret_cast<const float4*>(B + col0);
    const float bv[4] = {bb.x, bb.y, bb.z, bb.w};
#pragma unroll
    for (int i = 0; i < 8; i++) {
        int g = brow + row0 + i;
        if (g < NN) {
            float4 o;
            o.x = acc[i][0] + bv[0];
            o.y = acc[i][1] + bv[1];
            o.z = acc[i][2] + bv[2];
            o.w = acc[i][3] + bv[3];
            *reinterpret_cast<float4*>(H + (size_t)g * HID + col0) = o;
        }
    }
}

// ---------------- Aggregation: z = h + sum_{edges into node} w * h[src] ----------------
// 128 threads per node (one per channel); per edge the group reads one
// contiguous 512B row of h (coalesced). No atomics.

__global__ __launch_bounds__(256) void agg_kernel(const float* __restrict__ h,
                                                  const int* __restrict__ rp,
                                                  const int* __restrict__ cs,
                                                  const float* __restrict__ cw,
                                                  float* __restrict__ z) {
    const int node = blockIdx.x * 2 + (threadIdx.x >> 7);
    const int c = threadIdx.x & 127;
    float acc = h[(size_t)node * HID + c];  // (1+eps)*h with eps=0
    int k = rp[node];
    const int ke = rp[node + 1];
    for (; k < ke; k++) {
        int s = cs[k];
        float w = cw[k];
        acc = fmaf(w, h[(size_t)s * HID + c], acc);
    }
    z[(size_t)node * HID + c] = acc;
}

// ---------------- Fused MLP: h = relu(relu(z@W1+b1)@W2+b2) ----------------
// 256 thr, BM=32 rows, activations k-major in LDS, 4x4 micro-tile.

__global__ __launch_bounds__(256) void mlp_kernel(const float* __restrict__ Z,
                                                  const float* __restrict__ W1,
                                                  const float* __restrict__ B1,
                                                  const float* __restrict__ W2,
                                                  const float* __restrict__ B2,
                                                  float* __restrict__ H) {
    __shared__ float As[HID][36];  // k-major activations (z, then hidden)
    __shared__ float Wc[32][128];  // weight chunk
    const int tid = threadIdx.x;
    const int brow = blockIdx.x * 32;
    const int tr = tid >> 5, tc = tid & 31;
    const int row0 = tr * 4, col0 = tc * 4;

    // stage z tile (32 rows x 128) transposed into As
#pragma unroll
    for (int j = 0; j < 4; j++) {
        int f = tid + j * 256;   // float4 idx 0..1023
        int m = f >> 5;          // row 0..31
        int kk = (f & 31) << 2;  // 0..124
        int g = brow + m;
        float4 v = make_float4(0.f, 0.f, 0.f, 0.f);
        if (g < NN) v = *reinterpret_cast<const float4*>(Z + (size_t)g * HID + kk);
        As[kk + 0][m] = v.x; As[kk + 1][m] = v.y;
        As[kk + 2][m] = v.z; As[kk + 3][m] = v.w;
    }
    __syncthreads();

    float acc[4][4];
#pragma unroll
    for (int i = 0; i < 4; i++)
#pragma unroll
        for (int j = 0; j < 4; j++) acc[i][j] = 0.f;

    // GEMM1: hidden = z @ W1
    for (int k0 = 0; k0 < HID; k0 += 32) {
#pragma unroll
        for (int j = 0; j < 4; j++) {
            int f = tid + j * 256;
            int kk = f >> 5;
            int c4 = (f & 31) << 2;
            *reinterpret_cast<float4*>(&Wc[kk][c4]) =
                *reinterpret_cast<const float4*>(W1 + (size_t)(k0 + kk) * HID + c4);
        }
        __syncthreads();
#pragma unroll
        for (int kk = 0; kk < 32; kk++) {
            const float4 a = *reinterpret_cast<const float4*>(&As[k0 + kk][row0]);
            const float4 bb = *reinterpret_cast<const float4*>(&Wc[kk][col0]);
            float av[4] = {a.x, a.y, a.z, a.w};
            float bv[4] = {bb.x, bb.y, bb.z, bb.w};
#pragma unroll
            for (int i = 0; i < 4; i++)
#pragma unroll
                for (int j = 0; j < 4; j++) acc[i][j] = fmaf(av[i], bv[j], acc[i][j]);
        }
        __syncthreads();
    }

    // bias + relu, write hidden transposed back into As
    {
        const float4 bb = *reinterpret_cast<const float4*>(B1 + col0);
        const float bv[4] = {bb.x, bb.y, bb.z, bb.w};
#pragma unroll
        for (int i = 0; i < 4; i++)
#pragma unroll
            for (int j = 0; j < 4; j++) {
                float v = acc[i][j] + bv[j];
                As[col0 + j][row0 + i] = v > 0.f ? v : 0.f;
                acc[i][j] = 0.f;
            }
    }
    __syncthreads();

    // GEMM2: out = hidden @ W2
    for (int k0 = 0; k0 < HID; k0 += 32) {
#pragma unroll
        for (int j = 0; j < 4; j++) {
            int f = tid + j * 256;
            int kk = f >> 5;
            int c4 = (f & 31) << 2;
            *reinterpret_cast<float4*>(&Wc[kk][c4]) =
                *reinterpret_cast<const float4*>(W2 + (size_t)(k0 + kk) * HID + c4);
        }
        __syncthreads();
#pragma unroll
        for (int kk = 0; kk < 32; kk++) {
            const float4 a = *reinterpret_cast<const float4*>(&As[k0 + kk][row0]);
            const float4 bb = *reinterpret_cast<const float4*>(&Wc[kk][col0]);
            float av[4] = {a.x, a.y, a.z, a.w};
            float bv[4] = {bb.x, bb.y, bb.z, bb.w};
#pragma unroll
            for (int i = 0; i < 4; i++)
#pragma unroll
                for (int j = 0; j < 4; j++) acc[i][j] = fmaf(av[i], bv[j], acc[i][j]);
        }
        __syncthreads();
    }

    const float4 bb = *reinterpret_cast<const float4*>(B2 + col0);
    const float bv[4] = {bb.x, bb.y, bb.z, bb.w};
#pragma unroll
    for (int i = 0; i < 4; i++) {
        int g = brow + row0 + i;
        if (g < NN) {
            float4 o;
            o.x = fmaxf(acc[i][0] + bv[0], 0.f);
            o.y = fmaxf(acc[i][1] + bv[1], 0.f);
            o.z = fmaxf(acc[i][2] + bv[2], 0.f);
            o.w = fmaxf(acc[i][3] + bv[3], 0.f);
            *reinterpret_cast<float4*>(H + (size_t)g * HID + col0) = o;
        }
    }
}

// ---------------- Readout: out = h @ roW + rob ----------------
// one wave per row; lanes 0..39 own the 40 output columns.

__global__ __launch_bounds__(256) void readout_kernel(const float* __restrict__ h,
                                                      const float* __restrict__ W,
                                                      const float* __restrict__ B,
                                                      float* __restrict__ out) {
    __shared__ float Ws[HID * OUTD];  // 5120 floats
    __shared__ float Hr[4][HID];
    const int tid = threadIdx.x;
    const int wave = tid >> 6, lane = tid & 63;
    const int rbase = blockIdx.x * 4;
#pragma unroll
    for (int j = 0; j < 5; j++) {
        int f = tid + j * 256;  // 0..1279 float4s
        reinterpret_cast<float4*>(Ws)[f] = reinterpret_cast<const float4*>(W)[f];
    }
    if (tid < 128) {
        int r = tid >> 5;
        int c4 = (tid & 31) << 2;
        *reinterpret_cast<float4*>(&Hr[r][c4]) =
            *reinterpret_cast<const float4*>(h + (size_t)(rbase + r) * HID + c4);
    }
    __syncthreads();
    const int row = rbase + wave;
    if (lane < OUTD) {
        float acc = B[lane];
#pragma unroll
        for (int k = 0; k < HID; k++) acc = fmaf(Hr[wave][k], Ws[k * OUTD + lane], acc);
        out[(size_t)row * OUTD + lane] = acc;
    }
}

// ---------------- launch ----------------

extern "C" void kernel_launch(void* const* d_in, const int* in_sizes, int n_in,
                              void* d_out, int out_size, void* d_ws, size_t ws_size,
                              hipStream_t stream) {
    const float* features = (const float*)d_in[0];
    const int* src = (const int*)d_in[1];
    const int* dst = (const int*)d_in[2];
    const float* ew = (const float*)d_in[3];
    const float* embW = (const float*)d_in[4];
    const float* embB = (const float*)d_in[5];
    const float* W1 = (const float*)d_in[6];
    const float* B1 = (const float*)d_in[7];
    const float* W2 = (const float*)d_in[8];
    const float* B2 = (const float*)d_in[9];
    const float* roW = (const float*)d_in[10];
    const float* roB = (const float*)d_in[11];
    float* out = (float*)d_out;

    float* h = (float*)d_ws;                       // NN*HID
    float* z = h + (size_t)NN * HID;               // NN*HID
    int* rp = (int*)(z + (size_t)NN * HID);        // NN+1
    int* cursor = rp + (NN + 1);                   // NN
    int* deg = cursor + NN;                        // NN
    int* csr_src = deg + NN;                       // NE
    float* csr_w = (float*)(csr_src + NE);         // NE

    hipMemsetAsync(deg, 0, NN * sizeof(int), stream);
    count_kernel<<<(NE + 255) / 256, 256, 0, stream>>>(dst, deg);
    scan_kernel<<<1, 1024, 0, stream>>>(deg, rp, cursor);
    fill_kernel<<<(NE + 255) / 256, 256, 0, stream>>>(src, dst, ew, cursor, csr_src, csr_w);

    emb_gemm<<<(NN + 63) / 64, 256, 0, stream>>>(features, embW, embB, h);

    for (int l = 0; l < NL; l++) {
        agg_kernel<<<NN / 2, 256, 0, stream>>>(h, rp, csr_src, csr_w, z);
        mlp_kernel<<<(NN + 31) / 32, 256, 0, stream>>>(
            z, W1 + (size_t)l * HID * HID, B1 + (size_t)l * HID,
            W2 + (size_t)l * HID * HID, B2 + (size_t)l * HID, h);
    }

    readout_kernel<<<NN / 4, 256, 0, stream>>>(h, roW, roB, out);
}